// Round 4
// baseline (158.038 us; speedup 1.0000x reference)
//
#include <hip/hip_runtime.h>
#include <math.h>

#define EPS_F 1e-8f

typedef __attribute__((ext_vector_type(8))) short bf16x8;
typedef __attribute__((ext_vector_type(4))) float f32x4;

__device__ inline short f2bf(float f) {
    union { float f; unsigned u; } v; v.f = f;
    unsigned r = (v.u + 0x7fffu + ((v.u >> 16) & 1u)) >> 16;
    return (short)r;
}

// ---------------------------------------------------------------------------
// Kernel 1: per-batch small math, latency-optimized (unchanged from round 3).
// ---------------------------------------------------------------------------
__global__ __launch_bounds__(256) void prelim_kernel(
    const float* __restrict__ mu_prior,   // (16,128,32)
    const float* __restrict__ ls_prior,   // (16,128,32)
    const float* __restrict__ pi_prior,   // (16,32)
    const float* __restrict__ mu_post,    // (16,128)
    const float* __restrict__ ls_post,    // (16,128)
    const float* __restrict__ noise_c,    // (16,128)
    const float* __restrict__ noise_z,    // (16,128)
    const float* __restrict__ projW,      // (256,384)
    const float* __restrict__ projb,      // (256,)
    float* __restrict__ ws_bias,          // (16,256)
    float* __restrict__ kld_out)          // &out[16777216], pre-zeroed
{
    const int b = blockIdx.x;
    const int t = threadIdx.x;  // 0..255

    __shared__ float s_zpost[128];
    __shared__ float s_zc[128];
    __shared__ float s_mu[128];
    __shared__ float s_e2[128];
    __shared__ float s_lsp[128];
    __shared__ float s_kstd[128];
    __shared__ float s_p1[8][32];
    __shared__ float s_p2[8][32];

    if (t < 128) {
        const float mu = mu_post[b * 128 + t];
        const float ls = ls_post[b * 128 + t];
        const float el = __expf(ls);
        s_zpost[t] = mu + el * noise_c[b * 128 + t];
        s_zc[t]    = mu + (el + EPS_F) * noise_z[b * 128 + t];
        s_mu[t]    = mu;
        s_e2[t]    = el * el;
        s_lsp[t]   = ls;
        s_kstd[t]  = -ls + 0.5f * (el * el + mu * mu) - 0.5f;
    }
    __syncthreads();

    {
        const int c = t & 31;
        const int g = t >> 5;
        const float* mpB = mu_prior + b * 4096;
        const float* lpB = ls_prior + b * 4096;
        float lp = 0.f, kg = 0.f;
#pragma unroll 4
        for (int j = 0; j < 16; ++j) {
            const int d = g * 16 + j;
            const float mpr  = mpB[d * 32 + c];
            const float lpr  = lpB[d * 32 + c];
            const float inv2 = 0.5f * __expf(-2.f * lpr);
            const float zd   = s_zpost[d] - mpr;
            lp += -lpr - 0.91893853320467274f - zd * zd * inv2;
            const float dm   = s_mu[d] - mpr;
            const float e2pr = __expf(2.f * lpr);
            kg += lpr - s_lsp[d]
                + (s_e2[d] + dm * dm) * __builtin_amdgcn_rcpf(2.f * e2pr + EPS_F)
                - 0.5f;
        }
        s_p1[g][c] = lp;
        s_p2[g][c] = kg;
    }
    __syncthreads();

    if (t < 64) {
        const int c = t & 31;
        float lp = 0.f, kg = 0.f;
#pragma unroll
        for (int g = 0; g < 8; ++g) { lp += s_p1[g][c]; kg += s_p2[g][c]; }
        float ks = s_kstd[c] + s_kstd[c + 32] + s_kstd[c + 64] + s_kstd[c + 96];
        const float pp = pi_prior[b * 32 + c];

        float m = lp;
#pragma unroll
        for (int o = 16; o; o >>= 1) m = fmaxf(m, __shfl_xor(m, o, 32));
        const float e = __expf(lp - m);
        float den = e;
#pragma unroll
        for (int o = 16; o; o >>= 1) den += __shfl_xor(den, o, 32);
        const float pi = e * __builtin_amdgcn_rcpf(den);
        float tot = pi * kg + pi * (__logf(pi + EPS_F) - __logf(pp + EPS_F));
#pragma unroll
        for (int o = 16; o; o >>= 1) tot += __shfl_xor(tot, o, 32);
#pragma unroll
        for (int o = 16; o; o >>= 1) ks += __shfl_xor(ks, o, 32);
        if (t == 0) atomicAdd(kld_out, (tot + ks) * 0.0625f);
    }

    {
        const int o = t;
        const float4* wrow = (const float4*)(projW + o * 384 + 256);
        float sum = projb[o];
#pragma unroll 8
        for (int j = 0; j < 32; ++j) {
            const float4 w = wrow[j];
            sum += s_zc[4 * j + 0] * w.x + s_zc[4 * j + 1] * w.y +
                   s_zc[4 * j + 2] * w.z + s_zc[4 * j + 3] * w.w;
        }
        ws_bias[b * 256 + o] = sum;
    }
}

// ---------------------------------------------------------------------------
// Kernel 2: bf16 MFMA GEMM, occupancy-restructured.
// Tile 128x128xBK32, 256 threads = 4 waves (2 M x 2 N), wave tile 64x64 =
// 4x4 MFMA 16x16x32. Grid (32 nT, 2 oT, 16 b) = 1024 blocks -> 3-4 blocks/CU
// so independent barrier-groups cover each other's global-load stalls
// (round-3 512-thread version measured latency-bound at ~1 resident block).
// LDS fragment-major [kg][row][klo8]; all ds ops sequential b128.
// ---------------------------------------------------------------------------
__global__ __launch_bounds__(256) void gemm_kernel(
    const float* __restrict__ F,     // (16,256,4096) fp32
    const float* __restrict__ W,     // (256,384) fp32 ; Wf = cols 0..255
    const float* __restrict__ bias,  // (16,256)
    float* __restrict__ O)           // (16,256,4096)
{
    const int nT = blockIdx.x;  // 0..31  (HW tiles of 128)
    const int oT = blockIdx.y;  // 0..1   (O tiles of 128)
    const int b  = blockIdx.z;  // 0..15

    __shared__ short A_lds[4][128][8];  // [kg][m][klo]  8 KB
    __shared__ short B_lds[4][128][8];  // [kg][n][klo]  8 KB
    __shared__ float s_bias[128];

    const int tid  = threadIdx.x;
    const int lane = tid & 63;
    const int wave = tid >> 6;  // 0..3
    const int wm = wave & 1;    // M offset wm*64
    const int wn = wave >> 1;   // N offset wn*64

    const float* Fb = F + (size_t)b * 256 * 4096 + (size_t)nT * 128;

    // B staging: thread -> (n = tid&127, kg base = (tid>>7)*2); 16 k's x 1 n
    const int sbn  = tid & 127;
    const int sbkg = (tid >> 7) * 2;    // 0 or 2
    // A staging: thread -> (m = tid>>1, kg base = (tid&1)*2); 16 k's x 1 m
    const int sao  = tid >> 1;          // 0..127
    const int sakg = (tid & 1) * 2;     // 0 or 2

    if (tid < 128) s_bias[tid] = bias[b * 256 + oT * 128 + tid];

    const float* bptr = Fb + (size_t)(sbkg * 8) * 4096 + sbn;
    const float* aptr = W + (size_t)(oT * 128 + sao) * 384 + sakg * 8;

    float fb[16];
    float4 fa0, fa1, fa2, fa3;

    // preload chunk 0
#pragma unroll
    for (int i = 0; i < 16; ++i) fb[i] = bptr[(size_t)i * 4096];
    fa0 = *(const float4*)(aptr);
    fa1 = *(const float4*)(aptr + 4);
    fa2 = *(const float4*)(aptr + 8);
    fa3 = *(const float4*)(aptr + 12);

    f32x4 acc[4][4];
#pragma unroll
    for (int i = 0; i < 4; ++i)
#pragma unroll
        for (int j = 0; j < 4; ++j) acc[i][j] = (f32x4){0.f, 0.f, 0.f, 0.f};

    const int kg = lane >> 4;
    const int lm = lane & 15;

    for (int kc = 0; kc < 8; ++kc) {
        bf16x8 vb0, vb1, va0, va1;
#pragma unroll
        for (int i = 0; i < 8; ++i) vb0[i] = f2bf(fb[i]);
#pragma unroll
        for (int i = 0; i < 8; ++i) vb1[i] = f2bf(fb[8 + i]);
        va0[0] = f2bf(fa0.x); va0[1] = f2bf(fa0.y); va0[2] = f2bf(fa0.z); va0[3] = f2bf(fa0.w);
        va0[4] = f2bf(fa1.x); va0[5] = f2bf(fa1.y); va0[6] = f2bf(fa1.z); va0[7] = f2bf(fa1.w);
        va1[0] = f2bf(fa2.x); va1[1] = f2bf(fa2.y); va1[2] = f2bf(fa2.z); va1[3] = f2bf(fa2.w);
        va1[4] = f2bf(fa3.x); va1[5] = f2bf(fa3.y); va1[6] = f2bf(fa3.z); va1[7] = f2bf(fa3.w);

        __syncthreads();
        *(bf16x8*)&B_lds[sbkg][sbn][0]      = vb0;
        *(bf16x8*)&B_lds[sbkg + 1][sbn][0]  = vb1;
        *(bf16x8*)&A_lds[sakg][sao][0]      = va0;
        *(bf16x8*)&A_lds[sakg + 1][sao][0]  = va1;
        __syncthreads();

        // prefetch next chunk; overlaps frag reads + MFMA below
        if (kc < 7) {
            const float* bp = bptr + (size_t)(kc + 1) * 32 * 4096;
#pragma unroll
            for (int i = 0; i < 16; ++i) fb[i] = bp[(size_t)i * 4096];
            const float* ap = aptr + (kc + 1) * 32;
            fa0 = *(const float4*)(ap);
            fa1 = *(const float4*)(ap + 4);
            fa2 = *(const float4*)(ap + 8);
            fa3 = *(const float4*)(ap + 12);
        }

        bf16x8 aF[4], bF[4];
#pragma unroll
        for (int mt = 0; mt < 4; ++mt)
            aF[mt] = *(const bf16x8*)&A_lds[kg][wm * 64 + mt * 16 + lm][0];
#pragma unroll
        for (int nt = 0; nt < 4; ++nt)
            bF[nt] = *(const bf16x8*)&B_lds[kg][wn * 64 + nt * 16 + lm][0];

#pragma unroll
        for (int mt = 0; mt < 4; ++mt)
#pragma unroll
            for (int nt = 0; nt < 4; ++nt)
                acc[mt][nt] = __builtin_amdgcn_mfma_f32_16x16x32_bf16(
                    aF[mt], bF[nt], acc[mt][nt], 0, 0, 0);
    }

    // epilogue: + bias.  C/D: col = lane&15, row = (lane>>4)*4+reg
    float* Ob = O + (size_t)b * 256 * 4096 + (size_t)oT * 128 * 4096;
    const int rbase = wm * 64 + (lane >> 4) * 4;
    const int cbase = nT * 128 + wn * 64 + lm;
#pragma unroll
    for (int mt = 0; mt < 4; ++mt) {
#pragma unroll
        for (int r = 0; r < 4; ++r) {
            const int row = rbase + mt * 16 + r;
            const float bb = s_bias[row];
            float* orow = Ob + (size_t)row * 4096 + cbase;
#pragma unroll
            for (int nt = 0; nt < 4; ++nt)
                orow[nt * 16] = acc[mt][nt][r] + bb;
        }
    }
}

extern "C" void kernel_launch(void* const* d_in, const int* in_sizes, int n_in,
                              void* d_out, int out_size, void* d_ws, size_t ws_size,
                              hipStream_t stream) {
    const float* f_curr   = (const float*)d_in[0];  // (16,256,64,64)
    const float* mu_prior = (const float*)d_in[1];  // (16,128,32)
    const float* ls_prior = (const float*)d_in[2];  // (16,128,32)
    const float* pi_prior = (const float*)d_in[3];  // (16,32)
    const float* mu_post  = (const float*)d_in[4];  // (16,128)
    const float* ls_post  = (const float*)d_in[5];  // (16,128)
    const float* noise_c  = (const float*)d_in[6];  // (16,128)
    const float* noise_z  = (const float*)d_in[7];  // (16,128)
    const float* projW    = (const float*)d_in[8];  // (256,384)
    const float* projb    = (const float*)d_in[9];  // (256,)

    float* out = (float*)d_out;          // 16*256*64*64 f_out + 1 kld
    float* ws  = (float*)d_ws;
    float* ws_bias = ws;                 // 16*256 floats

    float* kld_out = out + 16777216;
    hipMemsetAsync(kld_out, 0, sizeof(float), stream);

    prelim_kernel<<<16, 256, 0, stream>>>(mu_prior, ls_prior, pi_prior, mu_post,
                                          ls_post, noise_c, noise_z, projW, projb,
                                          ws_bias, kld_out);
    gemm_kernel<<<dim3(32, 2, 16), 256, 0, stream>>>(f_curr, projW, ws_bias, out);
}